// Round 8
// baseline (563.045 us; speedup 1.0000x reference)
//
#include <hip/hip_runtime.h>
#include <hip/hip_bf16.h>

#define T_STEPS 2048
#define BATCH 16
#define DIM 1024
#define NDIM 64
#define M_TOTAL (T_STEPS * BATCH)  // 32768
#define STRIDE (BATCH * NDIM)      // floats per timestep = 1024
#define CH 64                      // recurrence chunk (timesteps per LDS buffer)
#define NLOG2E -1.44269504088896340736f

typedef __attribute__((ext_vector_type(8))) short bf16x8;
typedef __attribute__((ext_vector_type(4))) float f32x4;
typedef __attribute__((ext_vector_type(2))) float f32x2;

__device__ inline unsigned pk_bf(float lo, float hi) {
    __hip_bfloat162 h = __float22bfloat162_rn(float2{lo, hi});
    return *(unsigned*)&h;  // v_cvt_pk_bf16_f32
}

template <int CTRL>
__device__ inline float dpp_add(float x) {
    int v = __builtin_amdgcn_update_dpp(0, __float_as_int(x), CTRL, 0xF, 0xF, true);
    return x + __int_as_float(v);
}
// full sum across contiguous 16-lane rows (result in all 16 lanes)
__device__ inline float red16(float x) {
    x = dpp_add<0xB1>(x);
    x = dpp_add<0x4E>(x);
    x = dpp_add<0x141>(x);
    x = dpp_add<0x140>(x);
    return x;
}

#define AS1 __attribute__((address_space(1)))
#define AS3 __attribute__((address_space(3)))
__device__ inline void gl_lds16(const float* g, float* l) {
    __builtin_amdgcn_global_load_lds((const AS1 unsigned*)g, (AS3 unsigned*)l, 16, 0, 0);
}
#define WAIT_VM0 do { __builtin_amdgcn_s_waitcnt(0x0F70); asm volatile("" ::: "memory"); } while (0)

// ---------------- W prepack: fp32 -> bf16, row order [K, Q, V, A] ----------------
__global__ __launch_bounds__(256) void pack_w(
    const float* __restrict__ Wk, const float* __restrict__ Wq,
    const float* __restrict__ Wv, const float* __restrict__ Wa,
    unsigned short* __restrict__ Wb) {
    int n = blockIdx.x;  // 0..255
    int sel = n >> 6;
    const float* W = (sel == 0) ? Wk : (sel == 1) ? Wq : (sel == 2) ? Wv : Wa;
    int k4 = threadIdx.x * 4;
    float4 f = *(const float4*)(W + (size_t)(n & 63) * DIM + k4);
    uint2 u;
    u.x = pk_bf(f.x, f.y);
    u.y = pk_bf(f.z, f.w);
    *(uint2*)(Wb + (size_t)n * DIM + k4) = u;
}

// ---------------- projection ----------------
// 512 blocks x 256 thr. Block: 64 m-rows x 256 n (wave wn: 0=K 1=Q 2=V 3=A).
// BK=32, LDA=40 shorts (padded, 2-way bank alias = free). LDS double-buffered +
// register prefetch distance 2. K/Q written PRE-SHIFTED: Ksh[m-16] = k_m (i.e.
// Ksh[t] holds k_{t+1}); rows m<16 go to K0/Q0.
#define LDA 40
__global__ __launch_bounds__(256, 2) void proj_kernel(
    const float* __restrict__ x, const unsigned short* __restrict__ Wb,
    const float* __restrict__ ba, float* __restrict__ Ksh, float* __restrict__ Qsh,
    float* __restrict__ K0, float* __restrict__ Q0, float* __restrict__ VAi) {
    __shared__ unsigned short sA[2][64 * LDA];    // 10.2 KB
    __shared__ unsigned short sB[2][256 * LDA];   // 41 KB

    const int m0 = blockIdx.x * 64;
    const int tid = threadIdx.x;
    const int wn = tid >> 6, lane = tid & 63, lrow = lane & 15, quad = lane >> 4;

    f32x4 acc[4][4];  // [mt][nt]
#pragma unroll
    for (int a = 0; a < 4; a++)
#pragma unroll
        for (int b = 0; b < 4; b++) acc[a][b] = (f32x4)(0.f);

    const int ar = tid >> 2;
    const int acb = (tid & 3) * 8;
    const float* xg = x + (size_t)(m0 + ar) * DIM + acb;
    const unsigned short* wg = Wb + (size_t)tid * DIM;

    float4 a4[2][2];
    uint4 b4[2][4];
    auto load_globals = [&](int it, int slot) {
        const int k0 = it * 32;
        a4[slot][0] = *(const float4*)(xg + k0);
        a4[slot][1] = *(const float4*)(xg + k0 + 4);
#pragma unroll
        for (int j = 0; j < 4; ++j) b4[slot][j] = *(const uint4*)(wg + k0 + j * 8);
    };
    auto cvt_store = [&](int slot, int buf) {
        unsigned ap[4];
        ap[0] = pk_bf(a4[slot][0].x, a4[slot][0].y);
        ap[1] = pk_bf(a4[slot][0].z, a4[slot][0].w);
        ap[2] = pk_bf(a4[slot][1].x, a4[slot][1].y);
        ap[3] = pk_bf(a4[slot][1].z, a4[slot][1].w);
        *(uint4*)&sA[buf][ar * LDA + acb] = *(uint4*)&ap[0];
#pragma unroll
        for (int j = 0; j < 4; ++j)
            *(uint4*)&sB[buf][tid * LDA + j * 8] = b4[slot][j];
    };

    load_globals(0, 0);
    load_globals(1, 1);
    cvt_store(0, 0);
    __syncthreads();

    for (int it = 0; it < 32; ++it) {
        const int cur = it & 1;
        if (it + 2 < 32) load_globals(it + 2, cur);  // slot cur was consumed last iter

        bf16x8 af[4];
#pragma unroll
        for (int mt = 0; mt < 4; ++mt)
            af[mt] = *(const bf16x8*)&sA[cur][(mt * 16 + lrow) * LDA + quad * 8];
#pragma unroll
        for (int nt = 0; nt < 4; ++nt) {
            bf16x8 bfr = *(const bf16x8*)&sB[cur][(wn * 64 + nt * 16 + lrow) * LDA + quad * 8];
#pragma unroll
            for (int mt = 0; mt < 4; ++mt)
                acc[mt][nt] = __builtin_amdgcn_mfma_f32_16x16x32_bf16(af[mt], bfr, acc[mt][nt], 0, 0, 0);
        }

        if (it + 1 < 32) cvt_store((it + 1) & 1, cur ^ 1);  // loads have 1 full iter of slack
        __syncthreads();
    }

    // epilogue: C/D layout col = lane&15, row = quad*4 + reg  [m89-verified]
    float bav[4];
    if (wn == 3) {
#pragma unroll
        for (int nt = 0; nt < 4; ++nt) bav[nt] = ba[nt * 16 + lrow];
    }
#pragma unroll
    for (int mt = 0; mt < 4; ++mt)
#pragma unroll
        for (int nt = 0; nt < 4; ++nt) {
            int col = nt * 16 + lrow;
#pragma unroll
            for (int reg = 0; reg < 4; ++reg) {
                int m = m0 + mt * 16 + quad * 4 + reg;
                float vvv = acc[mt][nt][reg];
                if (wn == 0) {
                    float* dst = (m >= 16) ? (Ksh + (size_t)(m - 16) * 64) : (K0 + (size_t)m * 64);
                    dst[col] = vvv;
                } else if (wn == 1) {
                    float* dst = (m >= 16) ? (Qsh + (size_t)(m - 16) * 64) : (Q0 + (size_t)m * 64);
                    dst[col] = vvv;
                } else if (wn == 2) {
                    VAi[(size_t)m * 128 + col * 2] = vvv;
                } else {
                    VAi[(size_t)m * 128 + col * 2 + 1] = NLOG2E * (vvv + bav[nt]);
                }
            }
        }
}

// ---------------- c-precompute: c1=k_{t+1}.k_t, c2=q_{t+1}.k_t, c3=k_t.q_t ----------------
// Also backfills Ksh/Qsh row t=T-1 (clamped copy) so recur staging stays in-bounds.
__global__ __launch_bounds__(256) void cv_kernel(
    float* __restrict__ Ksh, float* __restrict__ Qsh,
    const float* __restrict__ K0, const float* __restrict__ Q0,
    float* __restrict__ Cv) {
    int m = blockIdx.x * 16 + (threadIdx.x >> 4);
    int c = threadIdx.x & 15;
    int t = m >> 4, b = m & 15;   // t == blockIdx.x (uniform per block)

    const float* kcp = (t == 0) ? (K0 + (size_t)b * 64) : (Ksh + (size_t)(m - 16) * 64);
    const float* qcp = (t == 0) ? (Q0 + (size_t)b * 64) : (Qsh + (size_t)(m - 16) * 64);
    float4 kc = *(const float4*)(kcp + c * 4);
    float4 qc = *(const float4*)(qcp + c * 4);
    bool last = (t == T_STEPS - 1);
    float4 kn, qn;
    if (last) { kn = kc; qn = qc; }
    else {
        kn = *(const float4*)(Ksh + (size_t)m * 64 + c * 4);
        qn = *(const float4*)(Qsh + (size_t)m * 64 + c * 4);
    }
    float c1 = red16(kn.x * kc.x + kn.y * kc.y + kn.z * kc.z + kn.w * kc.w);
    float c2 = red16(qn.x * kc.x + qn.y * kc.y + qn.z * kc.z + qn.w * kc.w);
    float c3 = red16(kc.x * qc.x + kc.y * qc.y + kc.z * qc.z + kc.w * qc.w);
    if (c == 0) *(float4*)(Cv + (size_t)m * 4) = float4{c1, c2, c3, 0.f};
    if (last) {  // backfill shifted arrays' final row
        *(float4*)(Ksh + (size_t)m * 64 + c * 4) = kc;
        *(float4*)(Qsh + (size_t)m * 64 + c * 4) = qc;
    }
}

// ---------------- recurrence (chain-broken) ----------------
// grid (16 row-groups, 16 batches) x 64; lane = r*16+c; row i = g*4+r, cols c*4..+3.
// Invariants at top of iter t: s = S_{t-1}, rkp = k_t.S_{t-1}, rq = q_t.S_{t-1},
// kc = k_t. Staged per t: Ksh->k_{t+1}, Qsh->q_{t+1}, VA->(v_t, abar_t), Cv->(c1,c2,c3).
__global__ __launch_bounds__(64, 1) void recur_kernel(
    const float* __restrict__ Ksh, const float* __restrict__ Qsh,
    const float* __restrict__ VAi, const float* __restrict__ Cv,
    const float* __restrict__ K0, const float* __restrict__ Q0,
    const float* __restrict__ S0, const float* __restrict__ d_alpha,
    float* __restrict__ out, float* __restrict__ Sout) {
    __shared__ float Kl[2][CH][64];   // 32 KB
    __shared__ float Ql[2][CH][64];   // 32 KB
    __shared__ float VAl[2][CH][8];   // 4 KB
    __shared__ float Cl[2][CH][4];    // 2 KB
    __shared__ float Ol[CH][4];       // 1 KB (raw o; silu at dump)

    int b = blockIdx.y, g = blockIdx.x, lane = threadIdx.x;
    int r = lane >> 4, c = lane & 15, i = g * 4 + r, c4 = c * 4;

    float4 sv = *(const float4*)(S0 + ((size_t)b * NDIM + i) * NDIM + c4);
    f32x2 s01 = {sv.x, sv.y}, s23 = {sv.z, sv.w};
    float dabar = d_alpha[i] * NLOG2E;

    const float* Kbase = Ksh + (size_t)b * NDIM + (size_t)(lane >> 4) * STRIDE + (lane & 15) * 4;
    const float* Qbase = Qsh + (size_t)b * NDIM + (size_t)(lane >> 4) * STRIDE + (lane & 15) * 4;
    const float* VAbase = VAi + (size_t)b * 128 + g * 8 + (lane & 1) * 4 + (size_t)(lane >> 1) * 2048;
    const float* Cbase = Cv + (size_t)b * 4 + (size_t)lane * 64;  // step stride = 16*4 floats

    auto load_chunk = [&](int t0, int buf) {
#pragma unroll
        for (int j = 0; j < 16; ++j) {
            gl_lds16(Kbase + (size_t)(t0 + j * 4) * STRIDE, &Kl[buf][j * 4][0]);
            gl_lds16(Qbase + (size_t)(t0 + j * 4) * STRIDE, &Ql[buf][j * 4][0]);
        }
        gl_lds16(VAbase + (size_t)t0 * 2048, &VAl[buf][0][0]);
        gl_lds16(VAbase + (size_t)(t0 + 32) * 2048, &VAl[buf][32][0]);
        gl_lds16(Cbase + (size_t)t0 * 64, &Cl[buf][0][0]);
    };

    load_chunk(0, 0);

    // prologue: rkp_0 = k_0.S0, rq_0 = q_0.S0, kc = k_0
    float4 k0v = *(const float4*)(K0 + (size_t)b * 64 + c4);
    float4 q0v = *(const float4*)(Q0 + (size_t)b * 64 + c4);
    f32x2 kc01 = {k0v.x, k0v.y}, kc23 = {k0v.z, k0v.w};
    f32x2 qA0 = {q0v.x, q0v.y}, qB0 = {q0v.z, q0v.w};
    f32x2 pk0 = kc01 * s01; pk0 = kc23 * s23 + pk0;
    f32x2 pq0 = qA0 * s01;  pq0 = qB0 * s23 + pq0;
    float rkp = red16(pk0.x + pk0.y);
    float rq  = red16(pq0.x + pq0.y);

    WAIT_VM0;

    // depth-2 LDS->reg pipeline
    f32x2 kn01[2], kn23[2], qn01[2], qn23[2], va[2];
    f32x4 cc[2];
#pragma unroll
    for (int u = 0; u < 2; ++u) {
        f32x4 kk = *(const f32x4*)(&Kl[0][u][c4]);
        f32x4 qq = *(const f32x4*)(&Ql[0][u][c4]);
        kn01[u] = kk.lo; kn23[u] = kk.hi;
        qn01[u] = qq.lo; qn23[u] = qq.hi;
        va[u] = *(const f32x2*)&VAl[0][u][r * 2];
        cc[u] = *(const f32x4*)&Cl[0][u][0];
    }

    for (int j = 0; j < T_STEPS / CH; ++j) {
        int cb = j & 1;
        if (j + 1 < T_STEPS / CH) load_chunk((j + 1) * CH, cb ^ 1);

        const float* Kb = &Kl[cb][0][0];
        const float* Qb = &Ql[cb][0][0];
        const float* Vb = &VAl[cb][0][0];
        const float* Cb = &Cl[cb][0][0];

#pragma unroll
        for (int tl = 0; tl < CH; ++tl) {
            int sl = tl & 1;
            f32x2 kA = kn01[sl], kB = kn23[sl], qA = qn01[sl], qB = qn23[sl];
            f32x2 vaa = va[sl];
            f32x4 c4v = cc[sl];
            if (tl < CH - 2) {
                f32x4 kk = *(const f32x4*)(Kb + (tl + 2) * 64 + c4);
                f32x4 qq = *(const f32x4*)(Qb + (tl + 2) * 64 + c4);
                kn01[sl] = kk.lo; kn23[sl] = kk.hi;
                qn01[sl] = qq.lo; qn23[sl] = qq.hi;
                va[sl] = *(const f32x2*)&Vb[(tl + 2) * 8 + r * 2];
                cc[sl] = *(const f32x4*)&Cb[(tl + 2) * 4];
            }

            // ---- alpha (chain head): alpha_t = sigmoid(da*rkp + a + ba)
            float e = __builtin_amdgcn_exp2f(fmaf(dabar, rkp, vaa.y));
            float alpha = __builtin_amdgcn_rcpf(1.f + e);
            float u1 = fmaf(-alpha, vaa.x, vaa.x);          // (1-alpha)*v

            // ---- output (off-chain): o = alpha*rq + u1*(k.q)
            float o = fmaf(alpha, rq, u1 * c4v.z);
            if (c == 0) Ol[tl][r] = o;

            // ---- dots vs S_{t-1} (off-chain, full step of slack)
            f32x2 pk = kA * s01; pk = kB * s23 + pk;
            f32x2 pq = qA * s01; pq = qB * s23 + pq;
            float g1 = pk.x + pk.y;
            float g2 = pq.x + pq.y;
            g1 = dpp_add<0xB1>(g1);  g2 = dpp_add<0xB1>(g2);
            g1 = dpp_add<0x4E>(g1);  g2 = dpp_add<0x4E>(g2);
            g1 = dpp_add<0x141>(g1); g2 = dpp_add<0x141>(g2);
            g1 = dpp_add<0x140>(g1); g2 = dpp_add<0x140>(g2);

            // ---- state update: S_t = alpha*S + u1*k_t
            f32x2 a2 = {alpha, alpha}, u2 = {u1, u1};
            s01 = a2 * s01 + u2 * kc01;
            s23 = a2 * s23 + u2 * kc23;

            // ---- recurrences: rk_{t+1} = alpha*g1 + u1*c1 ; rq_{t+1} = alpha*g2 + u1*c2
            rkp = fmaf(alpha, g1, u1 * c4v.x);
            rq  = fmaf(alpha, g2, u1 * c4v.y);

            kc01 = kA; kc23 = kB;  // k_{t+1} becomes current
        }
        WAIT_VM0;  // next chunk staged a full chunk ago

        // dump chunk outputs with silu: lane = local t, 4 rows
        float4 t4 = *(const float4*)&Ol[lane][0];
        t4.x = t4.x * t4.x * __builtin_amdgcn_rcpf(1.f + __builtin_amdgcn_exp2f(t4.x * NLOG2E));
        t4.y = t4.y * t4.y * __builtin_amdgcn_rcpf(1.f + __builtin_amdgcn_exp2f(t4.y * NLOG2E));
        t4.z = t4.z * t4.z * __builtin_amdgcn_rcpf(1.f + __builtin_amdgcn_exp2f(t4.z * NLOG2E));
        t4.w = t4.w * t4.w * __builtin_amdgcn_rcpf(1.f + __builtin_amdgcn_exp2f(t4.w * NLOG2E));
        *(float4*)(out + ((size_t)(j * CH + lane) * BATCH + b) * NDIM + g * 4) = t4;

        if (j + 1 < T_STEPS / CH) {  // preload pipeline for next chunk
            int nb = cb ^ 1;
#pragma unroll
            for (int u = 0; u < 2; ++u) {
                f32x4 kk = *(const f32x4*)(&Kl[nb][u][c4]);
                f32x4 qq = *(const f32x4*)(&Ql[nb][u][c4]);
                kn01[u] = kk.lo; kn23[u] = kk.hi;
                qn01[u] = qq.lo; qn23[u] = qq.hi;
                va[u] = *(const f32x2*)&VAl[nb][u][r * 2];
                cc[u] = *(const f32x4*)&Cl[nb][u][0];
            }
        }
    }

    float* so = Sout + ((size_t)b * NDIM + i) * NDIM + c4;
    *(float4*)so = float4{s01.x, s01.y, s23.x, s23.y};
}

extern "C" void kernel_launch(void* const* d_in, const int* in_sizes, int n_in,
                              void* d_out, int out_size, void* d_ws, size_t ws_size,
                              hipStream_t stream) {
    const float* x  = (const float*)d_in[0];
    const float* S0 = (const float*)d_in[1];
    const float* Wk = (const float*)d_in[2];
    const float* Wv = (const float*)d_in[3];
    const float* Wq = (const float*)d_in[4];
    const float* Wa = (const float*)d_in[5];
    const float* da = (const float*)d_in[6];
    const float* ba = (const float*)d_in[7];

    float* out = (float*)d_out;
    float* Sout = out + (size_t)T_STEPS * BATCH * NDIM;

    const size_t per = (size_t)M_TOTAL * NDIM;   // 2.1 M floats
    float* Ksh = (float*)d_ws;                   // per  (Ksh[t*16+b] = k_{t+1})
    float* Qsh = Ksh + per;                      // per
    float* VAi = Qsh + per;                      // 2*per (v, abar interleaved)
    float* Cv  = VAi + 2 * per;                  // M_TOTAL*4
    float* K0  = Cv + (size_t)M_TOTAL * 4;       // 16*64
    float* Q0  = K0 + 16 * 64;                   // 16*64
    unsigned short* Wb = (unsigned short*)(Q0 + 16 * 64);  // 512 KB

    pack_w<<<dim3(256), dim3(256), 0, stream>>>(Wk, Wq, Wv, Wa, Wb);
    proj_kernel<<<dim3(M_TOTAL / 64), dim3(256), 0, stream>>>(x, Wb, ba, Ksh, Qsh, K0, Q0, VAi);
    cv_kernel<<<dim3(T_STEPS), dim3(256), 0, stream>>>(Ksh, Qsh, K0, Q0, Cv);
    recur_kernel<<<dim3(16, BATCH), dim3(64), 0, stream>>>(Ksh, Qsh, VAi, Cv, K0, Q0, S0, da, out, Sout);
}